// Round 8
// baseline (24.853 us; speedup 1.0000x reference)
//
#include <hip/hip_runtime.h>
#include <math.h>

#define LAMBDA_OPACITY 0.001f
#define LAMBDA_DISTORTION 0.001f

// Fused NeRF loss, single dispatch. R6 structure + __launch_bounds__(256,8):
// force the allocator to a 64-VGPR budget so 8 waves/SIMD stay resident
// (waves halve at VGPR 64/128/256) — tests the latency-hiding theory.
// No nontemporal hints: inputs are Infinity-Cache-resident across replays (R5).
// Blocks [0, ray_blocks): distortion, 16 rays/block, 16 lanes/ray, 8 samples/lane.
// Blocks [ray_blocks, ...): dense float4 elementwise (rgb MSE + opacity entropy).
//
// Distortion identity: loss = 2*sum_{j<i} w_i w_j (t_i - t_j) + sum w^2 d / 3.
__global__ void __launch_bounds__(256, 8) fused_nerf_loss(
        const float* __restrict__ rgb,
        const float* __restrict__ target_rgb,
        const float* __restrict__ opacity,
        const float* __restrict__ ws,
        const float* __restrict__ deltas,
        const float* __restrict__ ts,
        const int* __restrict__ rays_a,
        float* __restrict__ out_rgb,
        float* __restrict__ out_op,
        float* __restrict__ out_dist,
        int n_rgb, int n_rays, int ray_blocks) {
    const int tid = threadIdx.x;

    if ((int)blockIdx.x >= ray_blocks) {
        // ---- dense elementwise blocks ----
        const int chunk = (blockIdx.x - ray_blocks) * 256 + tid;
        const int e = chunk * 4;
        if (e < n_rgb) {
            float4 a = *reinterpret_cast<const float4*>(rgb + e);
            float4 b = *reinterpret_cast<const float4*>(target_rgb + e);
            float4 r;
            r.x = (a.x - b.x) * (a.x - b.x);
            r.y = (a.y - b.y) * (a.y - b.y);
            r.z = (a.z - b.z) * (a.z - b.z);
            r.w = (a.w - b.w) * (a.w - b.w);
            *reinterpret_cast<float4*>(out_rgb + e) = r;
        } else if (e < n_rgb + n_rays) {
            const int oi = e - n_rgb;
            float4 o = *reinterpret_cast<const float4*>(opacity + oi);
            float ox = o.x + 1e-10f, oy = o.y + 1e-10f;
            float oz = o.z + 1e-10f, ow = o.w + 1e-10f;
            float4 r;
            r.x = LAMBDA_OPACITY * (-ox * logf(ox));
            r.y = LAMBDA_OPACITY * (-oy * logf(oy));
            r.z = LAMBDA_OPACITY * (-oz * logf(oz));
            r.w = LAMBDA_OPACITY * (-ow * logf(ow));
            *reinterpret_cast<float4*>(out_op + oi) = r;
        }
        return;
    }

    // ---- distortion blocks ----
    const int wave = tid >> 6;
    const int lane = tid & 63;
    const int sub  = lane & 15;   // lane within the ray's 16-lane group
    const int grp  = lane >> 4;   // which of 4 rays this wave handles
    const int ray  = blockIdx.x * 16 + wave * 4 + grp;
    if (ray >= n_rays) return;

    const int out_idx = rays_a[ray * 3 + 0];
    const int start   = rays_a[ray * 3 + 1];
    const int count   = rays_a[ray * 3 + 2];

    float acc = 0.f, carry_w = 0.f, carry_wt = 0.f;

    for (int base = 0; base < count; base += 128) {
        const int i0 = base + sub * 8;
        float w[8], t[8], dl[8];
        if (i0 + 8 <= count) {
            const float4 w0 = *reinterpret_cast<const float4*>(ws     + start + i0);
            const float4 w1 = *reinterpret_cast<const float4*>(ws     + start + i0 + 4);
            const float4 t0 = *reinterpret_cast<const float4*>(ts     + start + i0);
            const float4 t1 = *reinterpret_cast<const float4*>(ts     + start + i0 + 4);
            const float4 d0 = *reinterpret_cast<const float4*>(deltas + start + i0);
            const float4 d1 = *reinterpret_cast<const float4*>(deltas + start + i0 + 4);
            w[0]=w0.x; w[1]=w0.y; w[2]=w0.z; w[3]=w0.w;
            w[4]=w1.x; w[5]=w1.y; w[6]=w1.z; w[7]=w1.w;
            t[0]=t0.x; t[1]=t0.y; t[2]=t0.z; t[3]=t0.w;
            t[4]=t1.x; t[5]=t1.y; t[6]=t1.z; t[7]=t1.w;
            dl[0]=d0.x; dl[1]=d0.y; dl[2]=d0.z; dl[3]=d0.w;
            dl[4]=d1.x; dl[5]=d1.y; dl[6]=d1.z; dl[7]=d1.w;
        } else {
            #pragma unroll
            for (int k = 0; k < 8; ++k) {
                const int i = i0 + k;
                const bool v = (i < count);
                w[k]  = v ? ws[start + i]     : 0.f;
                t[k]  = v ? ts[start + i]     : 0.f;
                dl[k] = v ? deltas[start + i] : 0.f;
            }
        }

        // lane-local sequential prefix over 8 samples
        float lw = 0.f, lwt = 0.f, cpair = 0.f, csq = 0.f;
        #pragma unroll
        for (int k = 0; k < 8; ++k) {
            const float wk = w[k], tk = t[k];
            cpair += wk * (tk * lw - lwt);
            csq   += wk * wk * dl[k];
            lw  += wk;
            lwt += wk * tk;
        }

        // inclusive scan of (lw, lwt) within the 16-lane group
        float sw = lw, swt = lwt;
        #pragma unroll
        for (int off = 1; off < 16; off <<= 1) {
            const float pw  = __shfl_up(sw,  off, 16);
            const float pwt = __shfl_up(swt, off, 16);
            if (sub >= off) { sw += pw; swt += pwt; }
        }
        const float Pw  = sw  - lw  + carry_w;   // exclusive prefix
        const float Pwt = swt - lwt + carry_wt;

        acc += 2.f * (cpair + lwt * Pw - lw * Pwt) + csq * (1.f / 3.f);

        if (base + 128 < count) {
            carry_w  += __shfl(sw,  15, 16);
            carry_wt += __shfl(swt, 15, 16);
        }
    }

    // butterfly reduce within the 16-lane group
    #pragma unroll
    for (int off = 1; off < 16; off <<= 1)
        acc += __shfl_xor(acc, off, 16);

    if (sub == 0)
        out_dist[out_idx] = LAMBDA_DISTORTION * acc;
}

extern "C" void kernel_launch(void* const* d_in, const int* in_sizes, int n_in,
                              void* d_out, int out_size, void* d_ws, size_t ws_size,
                              hipStream_t stream) {
    const float* rgb        = (const float*)d_in[0];
    const float* target_rgb = (const float*)d_in[1];
    const float* opacity    = (const float*)d_in[2];
    const float* ws         = (const float*)d_in[3];
    const float* deltas     = (const float*)d_in[4];
    const float* ts         = (const float*)d_in[5];
    const int*   rays_a     = (const int*)d_in[6];

    const int n_rgb  = in_sizes[0];   // N_RAYS * 3
    const int n_rays = in_sizes[2];   // N_RAYS

    float* out      = (float*)d_out;
    float* out_rgb  = out;
    float* out_op   = out + n_rgb;
    float* out_dist = out + n_rgb + n_rays;

    const int ray_blocks = (n_rays + 15) / 16;                 // 16 rays/block
    const int ew_chunks  = (n_rgb + n_rays + 3) / 4;           // float4 chunks
    const int ew_blocks  = (ew_chunks + 255) / 256;
    const int blocks = ray_blocks + ew_blocks;

    fused_nerf_loss<<<blocks, 256, 0, stream>>>(
        rgb, target_rgb, opacity, ws, deltas, ts, rays_a,
        out_rgb, out_op, out_dist, n_rgb, n_rays, ray_blocks);
}

// Round 9
// 20.660 us; speedup vs baseline: 1.2030x; 1.2030x over previous
//
#include <hip/hip_runtime.h>
#include <math.h>

#define LAMBDA_OPACITY 0.001f
#define LAMBDA_DISTORTION 0.001f

// Fused NeRF loss, single dispatch.
// R6 structure + SPECULATIVE data prefetch: data loads are issued at the
// predicted address (start = ray*128, count = 128) in parallel with the
// rays_a header load, breaking the 2x-serialized HBM latency chain.
// Header is verified after the fact; mismatch falls into a generic cold
// path that is correct for arbitrary rays_a.
// No nontemporal hints (R5: inputs are L3-resident across replays).
// No launch_bounds min-wave forcing (R8: causes spills).
//
// Distortion identity: loss = 2*sum_{j<i} w_i w_j (t_i - t_j) + sum w^2 d / 3.
__global__ void __launch_bounds__(256) fused_nerf_loss(
        const float* __restrict__ rgb,
        const float* __restrict__ target_rgb,
        const float* __restrict__ opacity,
        const float* __restrict__ ws,
        const float* __restrict__ deltas,
        const float* __restrict__ ts,
        const int* __restrict__ rays_a,
        float* __restrict__ out_rgb,
        float* __restrict__ out_op,
        float* __restrict__ out_dist,
        int n_rgb, int n_rays, int ray_blocks) {
    const int tid = threadIdx.x;

    if ((int)blockIdx.x >= ray_blocks) {
        // ---- dense elementwise blocks ----
        const int chunk = (blockIdx.x - ray_blocks) * 256 + tid;
        const int e = chunk * 4;
        if (e < n_rgb) {
            float4 a = *reinterpret_cast<const float4*>(rgb + e);
            float4 b = *reinterpret_cast<const float4*>(target_rgb + e);
            float4 r;
            r.x = (a.x - b.x) * (a.x - b.x);
            r.y = (a.y - b.y) * (a.y - b.y);
            r.z = (a.z - b.z) * (a.z - b.z);
            r.w = (a.w - b.w) * (a.w - b.w);
            *reinterpret_cast<float4*>(out_rgb + e) = r;
        } else if (e < n_rgb + n_rays) {
            const int oi = e - n_rgb;
            float4 o = *reinterpret_cast<const float4*>(opacity + oi);
            float ox = o.x + 1e-10f, oy = o.y + 1e-10f;
            float oz = o.z + 1e-10f, ow = o.w + 1e-10f;
            float4 r;
            r.x = LAMBDA_OPACITY * (-ox * logf(ox));
            r.y = LAMBDA_OPACITY * (-oy * logf(oy));
            r.z = LAMBDA_OPACITY * (-oz * logf(oz));
            r.w = LAMBDA_OPACITY * (-ow * logf(ow));
            *reinterpret_cast<float4*>(out_op + oi) = r;
        }
        return;
    }

    // ---- distortion blocks ----
    const int wave = tid >> 6;
    const int lane = tid & 63;
    const int sub  = lane & 15;   // lane within the ray's 16-lane group
    const int grp  = lane >> 4;   // which of 4 rays this wave handles
    const int ray  = blockIdx.x * 16 + wave * 4 + grp;
    if (ray >= n_rays) return;

    // Speculative address: the canonical layout (verified below).
    const int spec_start = ray * 128;
    const int i0s = spec_start + sub * 8;

    // Issue data loads immediately — no dependency on the header load.
    const float4 w0 = *reinterpret_cast<const float4*>(ws     + i0s);
    const float4 w1 = *reinterpret_cast<const float4*>(ws     + i0s + 4);
    const float4 t0 = *reinterpret_cast<const float4*>(ts     + i0s);
    const float4 t1 = *reinterpret_cast<const float4*>(ts     + i0s + 4);
    const float4 d0 = *reinterpret_cast<const float4*>(deltas + i0s);
    const float4 d1 = *reinterpret_cast<const float4*>(deltas + i0s + 4);

    // Header load proceeds in parallel with the above.
    const int out_idx = rays_a[ray * 3 + 0];
    const int start   = rays_a[ray * 3 + 1];
    const int count   = rays_a[ray * 3 + 2];

    float acc = 0.f;

    if (start == spec_start && count == 128) {
        // ---- fast path: prefetched data is valid; exactly one chunk ----
        float w[8], t[8], dl[8];
        w[0]=w0.x; w[1]=w0.y; w[2]=w0.z; w[3]=w0.w;
        w[4]=w1.x; w[5]=w1.y; w[6]=w1.z; w[7]=w1.w;
        t[0]=t0.x; t[1]=t0.y; t[2]=t0.z; t[3]=t0.w;
        t[4]=t1.x; t[5]=t1.y; t[6]=t1.z; t[7]=t1.w;
        dl[0]=d0.x; dl[1]=d0.y; dl[2]=d0.z; dl[3]=d0.w;
        dl[4]=d1.x; dl[5]=d1.y; dl[6]=d1.z; dl[7]=d1.w;

        float lw = 0.f, lwt = 0.f, cpair = 0.f, csq = 0.f;
        #pragma unroll
        for (int k = 0; k < 8; ++k) {
            const float wk = w[k], tk = t[k];
            cpair += wk * (tk * lw - lwt);
            csq   += wk * wk * dl[k];
            lw  += wk;
            lwt += wk * tk;
        }

        float sw = lw, swt = lwt;
        #pragma unroll
        for (int off = 1; off < 16; off <<= 1) {
            const float pw  = __shfl_up(sw,  off, 16);
            const float pwt = __shfl_up(swt, off, 16);
            if (sub >= off) { sw += pw; swt += pwt; }
        }
        const float Pw  = sw  - lw;    // exclusive prefix (single chunk)
        const float Pwt = swt - lwt;

        acc = 2.f * (cpair + lwt * Pw - lw * Pwt) + csq * (1.f / 3.f);
    } else {
        // ---- cold generic path: arbitrary start/count ----
        float carry_w = 0.f, carry_wt = 0.f;
        for (int base = 0; base < count; base += 128) {
            const int i0 = base + sub * 8;
            float w[8], t[8], dl[8];
            #pragma unroll
            for (int k = 0; k < 8; ++k) {
                const int i = i0 + k;
                const bool v = (i < count);
                w[k]  = v ? ws[start + i]     : 0.f;
                t[k]  = v ? ts[start + i]     : 0.f;
                dl[k] = v ? deltas[start + i] : 0.f;
            }
            float lw = 0.f, lwt = 0.f, cpair = 0.f, csq = 0.f;
            #pragma unroll
            for (int k = 0; k < 8; ++k) {
                const float wk = w[k], tk = t[k];
                cpair += wk * (tk * lw - lwt);
                csq   += wk * wk * dl[k];
                lw  += wk;
                lwt += wk * tk;
            }
            float sw = lw, swt = lwt;
            #pragma unroll
            for (int off = 1; off < 16; off <<= 1) {
                const float pw  = __shfl_up(sw,  off, 16);
                const float pwt = __shfl_up(swt, off, 16);
                if (sub >= off) { sw += pw; swt += pwt; }
            }
            const float Pw  = sw  - lw  + carry_w;
            const float Pwt = swt - lwt + carry_wt;
            acc += 2.f * (cpair + lwt * Pw - lw * Pwt) + csq * (1.f / 3.f);
            if (base + 128 < count) {
                carry_w  += __shfl(sw,  15, 16);
                carry_wt += __shfl(swt, 15, 16);
            }
        }
    }

    // butterfly reduce within the 16-lane group
    #pragma unroll
    for (int off = 1; off < 16; off <<= 1)
        acc += __shfl_xor(acc, off, 16);

    if (sub == 0)
        out_dist[out_idx] = LAMBDA_DISTORTION * acc;
}

extern "C" void kernel_launch(void* const* d_in, const int* in_sizes, int n_in,
                              void* d_out, int out_size, void* d_ws, size_t ws_size,
                              hipStream_t stream) {
    const float* rgb        = (const float*)d_in[0];
    const float* target_rgb = (const float*)d_in[1];
    const float* opacity    = (const float*)d_in[2];
    const float* ws         = (const float*)d_in[3];
    const float* deltas     = (const float*)d_in[4];
    const float* ts         = (const float*)d_in[5];
    const int*   rays_a     = (const int*)d_in[6];

    const int n_rgb  = in_sizes[0];   // N_RAYS * 3
    const int n_rays = in_sizes[2];   // N_RAYS

    float* out      = (float*)d_out;
    float* out_rgb  = out;
    float* out_op   = out + n_rgb;
    float* out_dist = out + n_rgb + n_rays;

    const int ray_blocks = (n_rays + 15) / 16;                 // 16 rays/block
    const int ew_chunks  = (n_rgb + n_rays + 3) / 4;           // float4 chunks
    const int ew_blocks  = (ew_chunks + 255) / 256;
    const int blocks = ray_blocks + ew_blocks;

    fused_nerf_loss<<<blocks, 256, 0, stream>>>(
        rgb, target_rgb, opacity, ws, deltas, ts, rays_a,
        out_rgb, out_op, out_dist, n_rgb, n_rays, ray_blocks);
}